// Round 1
// baseline (1014.192 us; speedup 1.0000x reference)
//
#include <hip/hip_runtime.h>
#include <cstdint>

#define SIZE 1349
#define HALF 674
#define N2 (SIZE*SIZE)          // 1,819,801
#define LSIG 1000000
#define NB 8
#define NRINGS 1024             // actual max ring index is 953
#define CAP 6144                // max observed ring count ~4235; margin

// ---- phi2 key: bit-exact replication of the reference f32 op sequence ----
// phi2 = round(r)*2.0*PI + phi ; phi = arccos(x1/r)*sign(x2) (+PI if x2==0 & x1<0)
__device__ __forceinline__ uint32_t phi2_key(int a, int b, int* ring_out) {
#pragma clang fp contract(off)
    const float PI_F = 3.14159265358979323846f;   // == float32(np.pi) = 0x40490FDB
    float x1 = (float)a, x2 = (float)b;
    float rr = sqrtf(x1 * x1 + x2 * x2);          // exact int sum (<2^24), CR sqrt
    float ringf = rintf(rr);                      // np.round = half-to-even
    float phi;
    if (a == 0 && b == 0) {
        phi = 0.0f;                               // NaN->0, *sign(0)=0
    } else if (b == 0) {
        phi = (a < 0) ? PI_F : 0.0f;              // acos(+-1)*sign(0)=0, +PI if x1<0
    } else {
        float q = x1 / rr;                        // CR f32 division
        float ac = (float)::acos((double)q);      // ~CR float acos
        phi = (b > 0) ? ac : -ac;                 // * sign(x2), exact
    }
    float t = (2.0f * ringf) * PI_F;              // two f32 roundings, no fma
    float p2 = t + phi;                           // final f32 add
    *ring_out = (int)ringf;
    return __float_as_uint(p2);                   // p2 >= 0 -> bits are order-isomorphic
}

// ---- pass 1: count cells per ring ----
__global__ void k_count(uint32_t* __restrict__ ringCount) {
    __shared__ uint32_t h[NRINGS];
    for (int i = threadIdx.x; i < NRINGS; i += blockDim.x) h[i] = 0;
    __syncthreads();
    int g = blockIdx.x * blockDim.x + threadIdx.x;
    if (g < N2) {
        int a = g % SIZE - HALF, b = g / SIZE - HALF;
        float rr = sqrtf((float)(a * a + b * b));
        int k = (int)rintf(rr);
        atomicAdd(&h[k], 1u);
    }
    __syncthreads();
    for (int i = threadIdx.x; i < NRINGS; i += blockDim.x)
        if (h[i]) atomicAdd(&ringCount[i], h[i]);
}

// ---- pass 2: exclusive scan over 1024 ring counts (one block) ----
__global__ void k_scan(const uint32_t* __restrict__ ringCount,
                       uint32_t* __restrict__ ringOffset,
                       uint32_t* __restrict__ ringCursor) {
    __shared__ uint32_t s[NRINGS];
    int t = threadIdx.x;
    uint32_t mine = ringCount[t];
    s[t] = mine;
    __syncthreads();
    for (int d = 1; d < NRINGS; d <<= 1) {
        uint32_t x = (t >= d) ? s[t - d] : 0u;
        __syncthreads();
        s[t] += x;
        __syncthreads();
    }
    uint32_t excl = s[t] - mine;
    ringOffset[t] = excl;
    ringCursor[t] = excl;
}

// ---- pass 3: bucket (key,idx) pairs by ring ----
__global__ void k_fill(uint64_t* __restrict__ keys, uint32_t* __restrict__ ringCursor) {
    int g = blockIdx.x * blockDim.x + threadIdx.x;
    if (g >= N2) return;
    int a = g % SIZE - HALF, b = g / SIZE - HALF;
    int ring;
    uint32_t kb = phi2_key(a, b, &ring);
    uint32_t pos = atomicAdd(&ringCursor[ring], 1u);
    keys[pos] = ((uint64_t)kb << 32) | (uint32_t)g;  // idx in low bits = stable tiebreak
}

// ---- bitonic sort of S[0..P) ascending, P = pow2, blockDim = 1024 ----
__device__ __forceinline__ void bitonic(uint64_t* S, int P, int t) {
    for (int k2 = 2; k2 <= P; k2 <<= 1) {
        for (int j = k2 >> 1; j > 0; j >>= 1) {
            __syncthreads();
            for (int i = t; i < P; i += 1024) {
                int p = i ^ j;
                if (p > i) {
                    bool up = ((i & k2) == 0);
                    uint64_t x = S[i], y = S[p];
                    if ((x > y) == up) { S[i] = y; S[p] = x; }
                }
            }
        }
    }
    __syncthreads();
}

// ---- pass 4: per-ring sort -> global rank per cell ----
__global__ __launch_bounds__(1024) void k_sort(const uint64_t* __restrict__ keys,
                                               const uint32_t* __restrict__ ringOffset,
                                               const uint32_t* __restrict__ ringCount,
                                               uint32_t* __restrict__ rank) {
    __shared__ uint64_t S[CAP];
    int ringk = blockIdx.x;
    uint32_t off = ringOffset[ringk];
    uint32_t n = ringCount[ringk];
    if (n == 0) return;
    if (n > CAP) n = CAP;   // never expected; avoids LDS overflow
    int t = threadIdx.x;

    if (n <= 4096) {
        int P = 1;
        while (P < (int)n) P <<= 1;
        for (int i = t; i < P; i += 1024) S[i] = (i < (int)n) ? keys[off + i] : ~0ULL;
        __syncthreads();
        bitonic(S, P, t);
        for (int i = t; i < (int)n; i += 1024) {
            uint32_t g = (uint32_t)S[i];
            rank[g] = off + (uint32_t)i;
        }
    } else {
        int m = (int)n - 4096;  // <= 2048
        for (int i = t; i < 4096; i += 1024) S[i] = keys[off + i];
        for (int i = t; i < 2048; i += 1024) S[4096 + i] = (i < m) ? keys[off + 4096 + i] : ~0ULL;
        __syncthreads();
        bitonic(S, 4096, t);            // run A: S[0..4096)
        bitonic(S + 4096, 2048, t);     // run B: S[4096..6144) (pads at end)
        // rank-merge: all keys distinct (unique cell idx), pads = ~0 never < finite
        for (int i = t; i < 4096; i += 1024) {
            uint64_t v = S[i];
            int lo = 0, hi = m;
            while (lo < hi) { int mid = (lo + hi) >> 1; if (S[4096 + mid] < v) lo = mid + 1; else hi = mid; }
            rank[(uint32_t)v] = off + (uint32_t)(i + lo);
        }
        for (int j = t; j < m; j += 1024) {
            uint64_t v = S[4096 + j];
            int lo = 0, hi = 4096;
            while (lo < hi) { int mid = (lo + hi) >> 1; if (S[mid] < v) lo = mid + 1; else hi = mid; }
            rank[(uint32_t)v] = off + (uint32_t)(j + lo);
        }
    }
}

// ---- pass 5: gather into output grid ----
__global__ void k_gather(const float4* __restrict__ in,
                         const uint32_t* __restrict__ rank,
                         float4* __restrict__ out) {
    int idx = blockIdx.x * blockDim.x + threadIdx.x;  // over NB*N2
    if (idx >= NB * N2) return;
    int b = idx / N2;
    int g = idx - b * N2;
    uint32_t q = rank[g];
    float4 v;
    if (q < LSIG) {
        v = in[b * LSIG + q];
    } else {
        v = make_float4(0.f, 0.f, 0.f, 0.f);
    }
    out[idx] = v;
}

extern "C" void kernel_launch(void* const* d_in, const int* in_sizes, int n_in,
                              void* d_out, int out_size, void* d_ws, size_t ws_size,
                              hipStream_t stream) {
    const float* in = (const float*)d_in[0];
    float* out = (float*)d_out;
    uint8_t* ws = (uint8_t*)d_ws;

    // workspace layout (~21 MB total)
    constexpr size_t KEYS_OFF   = 0;                          // N2*8 = 14,558,408 B
    constexpr size_t RANK_OFF   = 14558464;                   // N2*4 =  7,279,204 B
    constexpr size_t COUNT_OFF  = 21837824;                   // 1024*4
    constexpr size_t OFFSET_OFF = COUNT_OFF + 4096;
    constexpr size_t CURSOR_OFF = OFFSET_OFF + 4096;

    uint64_t* keys       = (uint64_t*)(ws + KEYS_OFF);
    uint32_t* rank       = (uint32_t*)(ws + RANK_OFF);
    uint32_t* ringCount  = (uint32_t*)(ws + COUNT_OFF);
    uint32_t* ringOffset = (uint32_t*)(ws + OFFSET_OFF);
    uint32_t* ringCursor = (uint32_t*)(ws + CURSOR_OFF);

    hipMemsetAsync(ringCount, 0, NRINGS * sizeof(uint32_t), stream);

    int blocks = (N2 + 255) / 256;
    k_count<<<blocks, 256, 0, stream>>>(ringCount);
    k_scan<<<1, NRINGS, 0, stream>>>(ringCount, ringOffset, ringCursor);
    k_fill<<<blocks, 256, 0, stream>>>(keys, ringCursor);
    k_sort<<<954, 1024, 0, stream>>>(keys, ringOffset, ringCount, rank);

    int gblocks = (NB * N2 + 255) / 256;
    k_gather<<<gblocks, 256, 0, stream>>>((const float4*)in, rank, (float4*)out);
}

// Round 2
// 483.938 us; speedup vs baseline: 2.0957x; 2.0957x over previous
//
#include <hip/hip_runtime.h>
#include <cstdint>

#define SIZE 1349
#define HALF 674
#define N2 (SIZE*SIZE)          // 1,819,801
#define LSIG 1000000
#define NB 8
#define MAXRING 953
#define GRID_RINGS 954          // rings 0..953
#define CAP 6144                // max ring count ~4300 (proven <= 6144 in R1)

// ================= exact integer sqrt helpers =================
__device__ __forceinline__ int isqrt_i(int n) {
    int s = (int)sqrtf((float)n);
    while (s > 0 && s * s > n) s--;
    while ((s + 1) * (s + 1) <= n) s++;
    return s;
}

// Ring k row y (signed): cells with x^2+y^2 in [k(k-1)+1, k(k+1)], |x|<=674.
// returns 0 = empty, 1 = single interval [-xhi, xhi], 2 = double [-xhi,-xlo] u [xlo,xhi]
__device__ __forceinline__ int row_interval(int k, int y, int* xlo, int* xhi) {
    if (k == 0) { if (y == 0) { *xhi = 0; return 1; } return 0; }
    int yy = y * y;
    int B = k * (k + 1) - yy;
    if (B < 0) return 0;
    int h = isqrt_i(B);
    if (h > HALF) h = HALF;
    int A = k * (k - 1) + 1 - yy;
    *xhi = h;
    if (A <= 0) return 1;
    int f = isqrt_i(A);
    int lo = (f * f == A) ? f : f + 1;
    if (lo > h) return 0;
    *xlo = lo;
    return 2;
}

__device__ __forceinline__ uint32_t rowcnt(int k, int y) {
    int lo, hi;
    int kind = row_interval(k, y, &lo, &hi);
    if (kind == 0) return 0u;
    if (kind == 1) return (uint32_t)(2 * hi + 1);
    return (uint32_t)(2 * (hi - lo + 1));
}

// ================= pass 1: analytic per-ring counts =================
__global__ void k_prep1(uint32_t* __restrict__ ringCount) {
    __shared__ uint32_t red[256];
    int k = blockIdx.x, t = threadIdx.x;
    int ymaxv = min(k, HALF);
    int nrows = 2 * ymaxv + 1;
    uint32_t s = 0;
    for (int i = t; i < nrows; i += 256) s += rowcnt(k, i - ymaxv);
    red[t] = s;
    __syncthreads();
    for (int d = 128; d > 0; d >>= 1) { if (t < d) red[t] += red[t + d]; __syncthreads(); }
    if (t == 0) ringCount[k] = red[0];
}

// ================= pass 2: exclusive scan over ring counts =================
__global__ void k_prep2(const uint32_t* __restrict__ ringCount,
                        uint32_t* __restrict__ ringOffset) {
    __shared__ uint32_t s[1024];
    int t = threadIdx.x;
    uint32_t mine = (t < GRID_RINGS) ? ringCount[t] : 0u;
    s[t] = mine;
    __syncthreads();
    for (int d = 1; d < 1024; d <<= 1) {
        uint32_t x = (t >= d) ? s[t - d] : 0u;
        __syncthreads();
        s[t] += x;
        __syncthreads();
    }
    if (t < GRID_RINGS) ringOffset[t] = s[t] - mine;
}

// ================= bitonic sort, P = pow2, 1024 threads =================
__device__ __forceinline__ void bitonic(uint64_t* S, int P, int t) {
    for (int k2 = 2; k2 <= P; k2 <<= 1) {
        for (int j = k2 >> 1; j > 0; j >>= 1) {
            __syncthreads();
            for (int i = t; i < P; i += 1024) {
                int p = i ^ j;
                if (p > i) {
                    bool up = ((i & k2) == 0);
                    uint64_t x = S[i], y = S[p];
                    if ((x > y) == up) { S[i] = y; S[p] = x; }
                }
            }
        }
    }
    __syncthreads();
}

// ================= pass 3: generate + sort each ring in LDS =================
__global__ __launch_bounds__(1024) void k_sort(const uint32_t* __restrict__ ringOffset,
                                               uint32_t* __restrict__ rank) {
#pragma clang fp contract(off)
    __shared__ uint64_t S[CAP];
    __shared__ uint32_t ps[1024];   // inclusive scan of row-pair counts
    const float PI_F = 3.14159265358979323846f;
    int k = blockIdx.x, t = threadIdx.x;
    int ymaxv = min(k, HALF);
    int nrows = 2 * ymaxv + 1;
    uint32_t off = ringOffset[k];

    // ---- row-pair counts + block scan (rows indexed 0..nrows-1, y = idx - ymaxv) ----
    int i0 = 2 * t, i1 = 2 * t + 1;
    uint32_t c0 = (i0 < nrows) ? rowcnt(k, i0 - ymaxv) : 0u;
    uint32_t c1 = (i1 < nrows) ? rowcnt(k, i1 - ymaxv) : 0u;
    uint32_t pairsum = c0 + c1;
    ps[t] = pairsum;
    __syncthreads();
    for (int d = 1; d < 1024; d <<= 1) {
        uint32_t x = (t >= d) ? ps[t - d] : 0u;
        __syncthreads();
        ps[t] += x;
        __syncthreads();
    }
    int n = (int)ps[1023];          // ring cell count (<= CAP)

    // ---- generation: task = (halfrow y in [0,ymaxv]) x (side 0=neg,1=pos) ----
    // one acos serves both +y and -y rows: key(x,+y)=bits(t+ac), key(x,-y)=bits(t-ac)
    float tt = (2.0f * (float)k) * PI_F;   // same f32 roundings as ref: (round(r)*2)*PI
    int ntask = 2 * (ymaxv + 1);
    for (int task = t; task < ntask; task += 1024) {
        int y = task >> 1, side = task & 1;
        int xlo = 0, xhi = 0;
        int kind = row_interval(k, y, &xlo, &xhi);
        if (kind == 0) continue;
        int negcnt = (kind == 1) ? xhi : (xhi - xlo + 1);
        int xs, xe;
        if (side == 0) {
            if (negcnt == 0) continue;
            xs = -xhi; xe = (kind == 1) ? -1 : -xlo;
        } else {
            xs = (kind == 1) ? 0 : xlo; xe = xhi;
        }
        int ipos = y + ymaxv;            // row index of +y
        int ineg = ymaxv - y;            // row index of -y
        // exclusive row offset: pairExcl(i>>1) + (odd ? cnt(even row of pair) : 0)
        int pp = ipos >> 1;
        uint32_t basep = (pp ? ps[pp - 1] : 0u) + ((ipos & 1) ? rowcnt(k, (ipos & ~1) - ymaxv) : 0u);
        uint32_t basen = 0;
        if (y > 0) {
            int pn = ineg >> 1;
            basen = (pn ? ps[pn - 1] : 0u) + ((ineg & 1) ? rowcnt(k, (ineg & ~1) - ymaxv) : 0u);
        }
        if (side) { basep += (uint32_t)negcnt; basen += (uint32_t)negcnt; }

        int j = 0;
        for (int x = xs; x <= xe; ++x, ++j) {
            uint32_t kp, kn = 0;
            if (x == 0 && y == 0) {
                kp = 0u;                                  // phi2 = 0 at center
            } else if (y == 0) {
                float phi = (x < 0) ? PI_F : 0.0f;        // acos(+-1)*sign(0)=0; +PI if x<0
                kp = __float_as_uint(tt + phi);
            } else {
                int nn = x * x + y * y;
                float rr = sqrtf((float)nn);              // exact int -> CR sqrt
                float q = (float)x / rr;                  // CR f32 division
                float ac = (float)::acos((double)q);      // CR float acos (validated R1)
                kp = __float_as_uint(tt + ac);
                kn = __float_as_uint(tt - ac);
            }
            uint32_t gx = (uint32_t)(x + HALF);
            S[basep + j] = ((uint64_t)kp << 32) | (uint32_t)((y + HALF) * SIZE + gx);
            if (y > 0)
                S[basen + j] = ((uint64_t)kn << 32) | (uint32_t)((HALF - y) * SIZE + gx);
        }
    }

    // ---- sort + rank ----
    if (n <= 4096) {
        int P = 1;
        while (P < n) P <<= 1;
        for (int i = n + t; i < P; i += 1024) S[i] = ~0ULL;   // pad
        bitonic(S, P, t);                                     // starts with __syncthreads
        for (int i = t; i < n; i += 1024) {
            uint32_t g = (uint32_t)S[i];
            rank[g] = off + (uint32_t)i;
        }
    } else {
        int m = n - 4096;
        if (m > 2048) m = 2048;                               // cannot happen (proven R1)
        for (int i = n + t; i < CAP; i += 1024) S[i] = ~0ULL; // pad run B
        bitonic(S, 4096, t);                                  // run A
        bitonic(S + 4096, 2048, t);                           // run B
        // rank-merge (keys unique: idx in low bits)
        for (int i = t; i < 4096; i += 1024) {
            uint64_t v = S[i];
            int lo = 0, hi = m;
            while (lo < hi) { int mid = (lo + hi) >> 1; if (S[4096 + mid] < v) lo = mid + 1; else hi = mid; }
            rank[(uint32_t)v] = off + (uint32_t)(i + lo);
        }
        for (int jj = t; jj < m; jj += 1024) {
            uint64_t v = S[4096 + jj];
            int lo = 0, hi = 4096;
            while (lo < hi) { int mid = (lo + hi) >> 1; if (S[mid] < v) lo = mid + 1; else hi = mid; }
            rank[(uint32_t)v] = off + (uint32_t)(jj + lo);
        }
    }
}

// ================= pass 4: gather =================
__global__ void k_gather(const float4* __restrict__ in,
                         const uint32_t* __restrict__ rank,
                         float4* __restrict__ out) {
    int idx = blockIdx.x * blockDim.x + threadIdx.x;
    if (idx >= NB * N2) return;
    int b = idx / N2;
    int g = idx - b * N2;
    uint32_t q = rank[g];
    float4 v;
    if (q < LSIG) v = in[b * LSIG + q];
    else v = make_float4(0.f, 0.f, 0.f, 0.f);
    out[idx] = v;
}

extern "C" void kernel_launch(void* const* d_in, const int* in_sizes, int n_in,
                              void* d_out, int out_size, void* d_ws, size_t ws_size,
                              hipStream_t stream) {
    const float* in = (const float*)d_in[0];
    float* out = (float*)d_out;
    uint8_t* ws = (uint8_t*)d_ws;

    // workspace: rank (7.28 MB) + ring tables
    constexpr size_t RANK_OFF   = 0;                 // N2*4 = 7,279,204 -> pad
    constexpr size_t COUNT_OFF  = 7279616;           // 1024*4
    constexpr size_t OFFSET_OFF = COUNT_OFF + 4096;  // 1024*4

    uint32_t* rank       = (uint32_t*)(ws + RANK_OFF);
    uint32_t* ringCount  = (uint32_t*)(ws + COUNT_OFF);
    uint32_t* ringOffset = (uint32_t*)(ws + OFFSET_OFF);

    k_prep1<<<GRID_RINGS, 256, 0, stream>>>(ringCount);
    k_prep2<<<1, 1024, 0, stream>>>(ringCount, ringOffset);
    k_sort<<<GRID_RINGS, 1024, 0, stream>>>(ringOffset, rank);

    int gblocks = (NB * N2 + 255) / 256;
    k_gather<<<gblocks, 256, 0, stream>>>((const float4*)in, rank, (float4*)out);
}

// Round 3
// 397.429 us; speedup vs baseline: 2.5519x; 1.2177x over previous
//
#include <hip/hip_runtime.h>
#include <cstdint>

#define SIZE 1349
#define HALF 674
#define N2 (SIZE*SIZE)          // 1,819,801
#define LSIG 1000000
#define NB 8
#define GRID_RINGS 954          // rings 0..953 (corner r = 674*sqrt2 -> 953)
#define CAP 5376                // max ring cell count ~4350 (2*pi*674 + Gauss err)
#define MBUCKET 2048

// ================= exact integer sqrt =================
__device__ __forceinline__ int isqrt_i(int n) {
    int s = (int)sqrtf((float)n);
    while (s > 0 && s * s > n) s--;
    while ((s + 1) * (s + 1) <= n) s++;
    return s;
}

// Ring k row y: cells with x^2+y^2 in [k(k-1)+1, k(k+1)], |x|<=674.
// 0 = empty, 1 = single interval [-xhi,xhi], 2 = [-xhi,-xlo] u [xlo,xhi]
__device__ __forceinline__ int row_interval(int k, int y, int* xlo, int* xhi) {
    if (k == 0) { if (y == 0) { *xhi = 0; return 1; } return 0; }
    int yy = y * y;
    int B = k * (k + 1) - yy;
    if (B < 0) return 0;
    int h = isqrt_i(B);
    if (h > HALF) h = HALF;
    int A = k * (k - 1) + 1 - yy;
    *xhi = h;
    if (A <= 0) return 1;
    int f = isqrt_i(A);
    int lo = (f * f == A) ? f : f + 1;
    if (lo > h) return 0;
    *xlo = lo;
    return 2;
}

__device__ __forceinline__ uint32_t rowcnt(int k, int y) {
    int lo, hi;
    int kind = row_interval(k, y, &lo, &hi);
    if (kind == 0) return 0u;
    if (kind == 1) return (uint32_t)(2 * hi + 1);
    return (uint32_t)(2 * (hi - lo + 1));
}

// ================= pass 1: analytic per-ring counts =================
__global__ void k_prep1(uint32_t* __restrict__ ringCount) {
    __shared__ uint32_t red[256];
    int k = blockIdx.x, t = threadIdx.x;
    int ymaxv = min(k, HALF);
    int nrows = 2 * ymaxv + 1;
    uint32_t s = 0;
    for (int i = t; i < nrows; i += 256) s += rowcnt(k, i - ymaxv);
    red[t] = s;
    __syncthreads();
    for (int d = 128; d > 0; d >>= 1) { if (t < d) red[t] += red[t + d]; __syncthreads(); }
    if (t == 0) ringCount[k] = red[0];
}

// ================= pass 2: exclusive scan over ring counts =================
__global__ void k_prep2(const uint32_t* __restrict__ ringCount,
                        uint32_t* __restrict__ ringOffset) {
    __shared__ uint32_t s[1024];
    int t = threadIdx.x;
    uint32_t mine = (t < GRID_RINGS) ? ringCount[t] : 0u;
    s[t] = mine;
    __syncthreads();
    for (int d = 1; d < 1024; d <<= 1) {
        uint32_t x = (t >= d) ? s[t - d] : 0u;
        __syncthreads();
        s[t] += x;
        __syncthreads();
    }
    if (t < GRID_RINGS) ringOffset[t] = s[t] - mine;
}

// ================= bucket map: monotone in f32 key bits =================
// p2 - tt is Sterbenz-exact (p2 in [tt-pi, tt+pi] subset [tt/2, 2tt] for k>=1),
// +PI and *SC are monotone f32 ops, trunc monotone => bucket order == key order.
__device__ __forceinline__ int bucket_of(uint32_t kb, float tt) {
    const float PI_F = 3.14159265358979323846f;
    const float SC = 325.94932f;  // MBUCKET / (2*pi)
    float p2 = __uint_as_float(kb);
    float u = (p2 - tt) + PI_F;   // ~[0, 2pi]
    int b = (int)(u * SC);
    return min(max(b, 0), MBUCKET - 1);
}

// ================= ring enumeration (identical in both phases) =================
// PHASE 0: histogram buckets. PHASE 1: scatter (key,idx) into bucket slots.
template<int PHASE>
__device__ __forceinline__ void enum_ring(int k, int ymaxv, float tt, int t,
                                          uint32_t* cnt, uint32_t* boff, uint64_t* T) {
#pragma clang fp contract(off)
    const float PI_F = 3.14159265358979323846f;
    int ntask = 2 * (ymaxv + 1);
    for (int task = t; task < ntask; task += 1024) {
        int y = task >> 1, side = task & 1;
        int xlo = 0, xhi = 0;
        int kind = row_interval(k, y, &xlo, &xhi);
        if (kind == 0) continue;
        int xs, xe;
        if (side == 0) {
            xs = -xhi; xe = (kind == 1) ? -1 : -xlo;
            if (xe < xs) continue;
        } else {
            xs = (kind == 1) ? 0 : xlo; xe = xhi;
        }
        for (int x = xs; x <= xe; ++x) {
            uint32_t kp, kn = 0;
            if (y == 0) {
                float phi = (x < 0) ? PI_F : 0.0f;   // acos(+-1)*sign(0)=0; +PI if x<0
                kp = __float_as_uint(tt + phi);
            } else {
                int nn = x * x + y * y;
                float rr = sqrtf((float)nn);          // exact int -> CR sqrt
                float q = (float)x / rr;              // CR f32 division
                float ac = (float)::acos((double)q);  // CR float acos (validated R1/R2)
                kp = __float_as_uint(tt + ac);
                kn = __float_as_uint(tt - ac);
            }
            uint32_t gx = (uint32_t)(x + HALF);
            uint32_t gp = (uint32_t)(y + HALF) * SIZE + gx;
            int bp = bucket_of(kp, tt);
            if (PHASE == 0) atomicAdd(&cnt[bp], 1u);
            else { uint32_t p = atomicAdd(&boff[bp], 1u); T[p] = ((uint64_t)kp << 32) | gp; }
            if (y > 0) {
                uint32_t gn = (uint32_t)(HALF - y) * SIZE + gx;
                int bn = bucket_of(kn, tt);
                if (PHASE == 0) atomicAdd(&cnt[bn], 1u);
                else { uint32_t p = atomicAdd(&boff[bn], 1u); T[p] = ((uint64_t)kn << 32) | gn; }
            }
        }
    }
}

// ================= pass 3: per-ring bucket-count ranking =================
__global__ __launch_bounds__(1024) void k_rank(const uint32_t* __restrict__ ringOffset,
                                               const uint32_t* __restrict__ ringCount,
                                               uint32_t* __restrict__ rank) {
#pragma clang fp contract(off)
    __shared__ uint64_t T[CAP];          // 43 KB
    __shared__ uint32_t cnt[MBUCKET];    // 8 KB
    __shared__ uint32_t boff[MBUCKET];   // 8 KB
    __shared__ uint32_t ps[1024];        // 4 KB  (total 63 KB -> 2 blocks/CU)
    const float PI_F = 3.14159265358979323846f;
    int k = blockIdx.x, t = threadIdx.x;
    if (k == 0) { if (t == 0) rank[HALF * SIZE + HALF] = 0u; return; }
    int ymaxv = min(k, HALF);
    uint32_t off = ringOffset[k];
    int n = (int)ringCount[k];
    float tt = (2.0f * (float)k) * PI_F;  // same f32 roundings as ref

    cnt[2 * t] = 0u; cnt[2 * t + 1] = 0u;
    __syncthreads();

    enum_ring<0>(k, ymaxv, tt, t, cnt, boff, T);   // histogram
    __syncthreads();

    // exclusive scan of cnt[0..2048) via pair-sums + Hillis-Steele over 1024
    uint32_t c0 = cnt[2 * t], c1 = cnt[2 * t + 1];
    uint32_t s = c0 + c1;
    ps[t] = s;
    __syncthreads();
    for (int d = 1; d < 1024; d <<= 1) {
        uint32_t x = (t >= d) ? ps[t - d] : 0u;
        __syncthreads();
        ps[t] += x;
        __syncthreads();
    }
    uint32_t excl = ps[t] - s;
    boff[2 * t] = excl;
    boff[2 * t + 1] = excl + c0;
    __syncthreads();

    enum_ring<1>(k, ymaxv, tt, t, cnt, boff, T);   // scatter; boff[b] -> bucket end
    __syncthreads();

    // rank = ringOff + bucketStart + (# bucket members with smaller (key,idx))
    for (int i = t; i < n; i += 1024) {
        uint64_t v = T[i];
        uint32_t kb = (uint32_t)(v >> 32);
        int b = bucket_of(kb, tt);
        uint32_t end = boff[b];
        uint32_t start = end - cnt[b];
        uint32_t c = 0;
        for (uint32_t j = start; j < end; ++j) c += (T[j] < v) ? 1u : 0u;
        rank[(uint32_t)v] = off + start + c;
    }
}

// ================= pass 4: gather (1 thread = 1 cell, all 8 batches) =================
typedef float vfloat4 __attribute__((ext_vector_type(4)));

__global__ void k_gather(const vfloat4* __restrict__ in,
                         const uint32_t* __restrict__ rank,
                         vfloat4* __restrict__ out) {
    int g = blockIdx.x * blockDim.x + threadIdx.x;
    if (g >= N2) return;
    uint32_t q = rank[g];
    if (q < LSIG) {
#pragma unroll
        for (int b = 0; b < NB; ++b) {
            vfloat4 v = in[b * LSIG + (int)q];
            __builtin_nontemporal_store(v, &out[b * N2 + g]);
        }
    } else {
        vfloat4 z = {0.f, 0.f, 0.f, 0.f};
#pragma unroll
        for (int b = 0; b < NB; ++b)
            __builtin_nontemporal_store(z, &out[b * N2 + g]);
    }
}

extern "C" void kernel_launch(void* const* d_in, const int* in_sizes, int n_in,
                              void* d_out, int out_size, void* d_ws, size_t ws_size,
                              hipStream_t stream) {
    const float* in = (const float*)d_in[0];
    float* out = (float*)d_out;
    uint8_t* ws = (uint8_t*)d_ws;

    constexpr size_t RANK_OFF   = 0;                 // N2*4 = 7,279,204 -> pad
    constexpr size_t COUNT_OFF  = 7279616;           // 1024*4
    constexpr size_t OFFSET_OFF = COUNT_OFF + 4096;  // 1024*4

    uint32_t* rank       = (uint32_t*)(ws + RANK_OFF);
    uint32_t* ringCount  = (uint32_t*)(ws + COUNT_OFF);
    uint32_t* ringOffset = (uint32_t*)(ws + OFFSET_OFF);

    k_prep1<<<GRID_RINGS, 256, 0, stream>>>(ringCount);
    k_prep2<<<1, 1024, 0, stream>>>(ringCount, ringOffset);
    k_rank<<<GRID_RINGS, 1024, 0, stream>>>(ringOffset, ringCount, rank);

    int gblocks = (N2 + 255) / 256;
    k_gather<<<gblocks, 256, 0, stream>>>((const vfloat4*)in, rank, (vfloat4*)out);
}